// Round 1
// baseline (417.327 us; speedup 1.0000x reference)
//
#include <hip/hip_runtime.h>

#define C_GMS 0.0026f

__device__ __forceinline__ void mnmx(float& a, float& b) {
    float t = fminf(a, b);
    b = fmaxf(a, b);
    a = t;
}

// Exact median of 9 via the classic 19-exchange network.
__device__ __forceinline__ float median9(float p0, float p1, float p2,
                                         float p3, float p4, float p5,
                                         float p6, float p7, float p8) {
    mnmx(p1, p2); mnmx(p4, p5); mnmx(p7, p8);
    mnmx(p0, p1); mnmx(p3, p4); mnmx(p6, p7);
    mnmx(p1, p2); mnmx(p4, p5); mnmx(p7, p8);
    mnmx(p0, p3); mnmx(p5, p8); mnmx(p4, p7);
    mnmx(p3, p6); mnmx(p1, p4); mnmx(p2, p5);
    mnmx(p4, p7); mnmx(p4, p2); mnmx(p6, p4);
    mnmx(p4, p2);
    return p4;
}

// Grayscale both inputs: gray = mean over the 3 channels.
__global__ void gray_kernel(const float* __restrict__ Ii, const float* __restrict__ Ir,
                            float* __restrict__ gx, float* __restrict__ gy,
                            int HW, int total) {
    int idx = blockIdx.x * blockDim.x + threadIdx.x;
    if (idx >= total) return;
    int b = idx / HW;
    int p = idx - b * HW;
    const float* a = Ii + (size_t)b * 3 * HW + p;
    const float* r = Ir + (size_t)b * 3 * HW + p;
    gx[idx] = (a[0] + a[HW] + a[2 * HW]) * (1.0f / 3.0f);
    gy[idx] = (r[0] + r[HW] + r[2 * HW]) * (1.0f / 3.0f);
}

// 2x2 average pool on both grayscale images (channel-mean commutes with pool).
__global__ void down_kernel(const float* __restrict__ sx, const float* __restrict__ sy,
                            float* __restrict__ dx, float* __restrict__ dy,
                            int Ws, int Hd, int Wd, int total) {
    int idx = blockIdx.x * blockDim.x + threadIdx.x;
    if (idx >= total) return;
    int j = idx % Wd;
    int t = idx / Wd;
    int i = t % Hd;
    int b = t / Hd;
    size_t o = ((size_t)b * (Hd * 2) + i * 2) * Ws + j * 2;
    dx[idx] = (sx[o] + sx[o + 1] + sx[o + Ws] + sx[o + Ws + 1]) * 0.25f;
    dy[idx] = (sy[o] + sy[o + 1] + sy[o + Ws] + sy[o + Ws + 1]) * 0.25f;
}

// Fused median3(zero-pad) -> Prewitt(VALID) -> GMS map -> block reduce.
// 16x16 output tile; needs 20x20 gray window, 18x18 medians.
__global__ __launch_bounds__(256) void gms_kernel(const float* __restrict__ gx,
                                                  const float* __restrict__ gy,
                                                  int H, int W,
                                                  double* __restrict__ acc) {
    __shared__ float sx[20][20];
    __shared__ float sy[20][20];
    __shared__ float mx[18][18];
    __shared__ float my[18][18];

    const int tx = threadIdx.x, ty = threadIdx.y;
    const int tid = ty * 16 + tx;
    const int OI = blockIdx.y * 16, OJ = blockIdx.x * 16;
    const int b = blockIdx.z;
    const float* X = gx + (size_t)b * H * W;
    const float* Y = gy + (size_t)b * H * W;

    for (int l = tid; l < 400; l += 256) {
        int lr = l / 20, lc = l - lr * 20;
        int gr = OI - 1 + lr, gc = OJ - 1 + lc;
        bool in = (gr >= 0) && (gr < H) && (gc >= 0) && (gc < W);
        size_t o = (size_t)gr * W + gc;
        sx[lr][lc] = in ? X[o] : 0.0f;
        sy[lr][lc] = in ? Y[o] : 0.0f;
    }
    __syncthreads();

    for (int l = tid; l < 324; l += 256) {
        int mr = l / 18, mc = l - mr * 18;
        mx[mr][mc] = median9(sx[mr][mc],     sx[mr][mc + 1],     sx[mr][mc + 2],
                             sx[mr + 1][mc], sx[mr + 1][mc + 1], sx[mr + 1][mc + 2],
                             sx[mr + 2][mc], sx[mr + 2][mc + 1], sx[mr + 2][mc + 2]);
        my[mr][mc] = median9(sy[mr][mc],     sy[mr][mc + 1],     sy[mr][mc + 2],
                             sy[mr + 1][mc], sy[mr + 1][mc + 1], sy[mr + 1][mc + 2],
                             sy[mr + 2][mc], sy[mr + 2][mc + 1], sy[mr + 2][mc + 2]);
    }
    __syncthreads();

    float val = 0.0f;
    int i = OI + ty, j = OJ + tx;
    if (i < H - 2 && j < W - 2) {
        // Prewitt (cross-correlation, VALID): Gx = (right col - left col)/3,
        // Gy = (top row - bottom row)/3.
        float a00 = mx[ty][tx],     a01 = mx[ty][tx + 1],     a02 = mx[ty][tx + 2];
        float a10 = mx[ty + 1][tx],                           a12 = mx[ty + 1][tx + 2];
        float a20 = mx[ty + 2][tx], a21 = mx[ty + 2][tx + 1], a22 = mx[ty + 2][tx + 2];
        float GxI = ((a02 + a12 + a22) - (a00 + a10 + a20)) * (1.0f / 3.0f);
        float GyI = ((a00 + a01 + a02) - (a20 + a21 + a22)) * (1.0f / 3.0f);
        float gI = sqrtf(GxI * GxI + GyI * GyI);

        float b00 = my[ty][tx],     b01 = my[ty][tx + 1],     b02 = my[ty][tx + 2];
        float b10 = my[ty + 1][tx],                           b12 = my[ty + 1][tx + 2];
        float b20 = my[ty + 2][tx], b21 = my[ty + 2][tx + 1], b22 = my[ty + 2][tx + 2];
        float GxR = ((b02 + b12 + b22) - (b00 + b10 + b20)) * (1.0f / 3.0f);
        float GyR = ((b00 + b01 + b02) - (b20 + b21 + b22)) * (1.0f / 3.0f);
        float gR = sqrtf(GxR * GxR + GyR * GyR);

        val = 1.0f - (2.0f * gI * gR + C_GMS) / (gI * gI + gR * gR + C_GMS);
    }

    // wave64 shuffle reduce, then cross-wave via LDS, one double atomic/block
    for (int off = 32; off > 0; off >>= 1) val += __shfl_down(val, off);
    __shared__ float wsum[4];
    int lane = tid & 63, wid = tid >> 6;
    if (lane == 0) wsum[wid] = val;
    __syncthreads();
    if (tid == 0) {
        float s = wsum[0] + wsum[1] + wsum[2] + wsum[3];
        atomicAdd(acc, (double)s);
    }
}

__global__ void finalize_kernel(const double* __restrict__ acc, float* __restrict__ out) {
    if (blockIdx.x == 0 && threadIdx.x == 0) {
        double c0 = 16.0 * 510.0 * 510.0;
        double c1 = 16.0 * 254.0 * 254.0;
        double c2 = 16.0 * 126.0 * 126.0;
        double c3 = 16.0 * 62.0 * 62.0;
        double t = acc[0] / c0 + acc[1] / c1 + acc[2] / c2 + acc[3] / c3;
        out[0] = (float)(t * 0.25);
    }
}

extern "C" void kernel_launch(void* const* d_in, const int* in_sizes, int n_in,
                              void* d_out, int out_size, void* d_ws, size_t ws_size,
                              hipStream_t stream) {
    const float* Ii = (const float*)d_in[0];
    const float* Ir = (const float*)d_in[1];
    float* out = (float*)d_out;

    const int B = 16;
    const size_t N0 = (size_t)B * 512 * 512;
    const size_t N1 = (size_t)B * 256 * 256;
    const size_t N2 = (size_t)B * 128 * 128;
    const size_t N3 = (size_t)B * 64 * 64;

    char* ws = (char*)d_ws;
    double* acc = (double*)ws;           // 4 doubles
    float* buf = (float*)(ws + 256);
    float* X0 = buf;            float* Y0 = X0 + N0;
    float* X1 = Y0 + N0;        float* Y1 = X1 + N1;
    float* X2 = Y1 + N1;        float* Y2 = X2 + N2;
    float* X3 = Y2 + N2;        float* Y3 = X3 + N3;

    hipMemsetAsync(acc, 0, 4 * sizeof(double), stream);

    gray_kernel<<<(int)((N0 + 255) / 256), 256, 0, stream>>>(Ii, Ir, X0, Y0, 512 * 512, (int)N0);

    // scale 0
    {
        dim3 grid((510 + 15) / 16, (510 + 15) / 16, B);
        gms_kernel<<<grid, dim3(16, 16), 0, stream>>>(X0, Y0, 512, 512, acc + 0);
    }
    down_kernel<<<(int)((N1 + 255) / 256), 256, 0, stream>>>(X0, Y0, X1, Y1, 512, 256, 256, (int)N1);
    // scale 1
    {
        dim3 grid((254 + 15) / 16, (254 + 15) / 16, B);
        gms_kernel<<<grid, dim3(16, 16), 0, stream>>>(X1, Y1, 256, 256, acc + 1);
    }
    down_kernel<<<(int)((N2 + 255) / 256), 256, 0, stream>>>(X1, Y1, X2, Y2, 256, 128, 128, (int)N2);
    // scale 2
    {
        dim3 grid((126 + 15) / 16, (126 + 15) / 16, B);
        gms_kernel<<<grid, dim3(16, 16), 0, stream>>>(X2, Y2, 128, 128, acc + 2);
    }
    down_kernel<<<(int)((N3 + 255) / 256), 256, 0, stream>>>(X2, Y2, X3, Y3, 128, 64, 64, (int)N3);
    // scale 3
    {
        dim3 grid((62 + 15) / 16, (62 + 15) / 16, B);
        gms_kernel<<<grid, dim3(16, 16), 0, stream>>>(X3, Y3, 64, 64, acc + 3);
    }

    finalize_kernel<<<1, 64, 0, stream>>>(acc, out);
}

// Round 2
// 211.582 us; speedup vs baseline: 1.9724x; 1.9724x over previous
//
#include <hip/hip_runtime.h>

#define C_GMS 0.0026f

__device__ __forceinline__ void mnmx(float& a, float& b) {
    float t = fminf(a, b);
    b = fmaxf(a, b);
    a = t;
}

// Exact median of 9 via the classic 19-exchange network.
__device__ __forceinline__ float median9(float p0, float p1, float p2,
                                         float p3, float p4, float p5,
                                         float p6, float p7, float p8) {
    mnmx(p1, p2); mnmx(p4, p5); mnmx(p7, p8);
    mnmx(p0, p1); mnmx(p3, p4); mnmx(p6, p7);
    mnmx(p1, p2); mnmx(p4, p5); mnmx(p7, p8);
    mnmx(p0, p3); mnmx(p5, p8); mnmx(p4, p7);
    mnmx(p3, p6); mnmx(p1, p4); mnmx(p2, p5);
    mnmx(p4, p7); mnmx(p4, p2); mnmx(p6, p4);
    mnmx(p4, p2);
    return p4;
}

// Grayscale both inputs: gray = mean over 3 channels. float4-vectorized.
__global__ void gray_kernel(const float* __restrict__ Ii, const float* __restrict__ Ir,
                            float* __restrict__ gx, float* __restrict__ gy,
                            int HW4, int total4) {
    int idx = blockIdx.x * blockDim.x + threadIdx.x;
    if (idx >= total4) return;
    int b = idx / HW4;
    int p4 = idx - b * HW4;              // float4 index within image
    const float4* a = (const float4*)(Ii + (size_t)b * 3 * HW4 * 4) + p4;
    const float4* r = (const float4*)(Ir + (size_t)b * 3 * HW4 * 4) + p4;
    float4 a0 = a[0], a1 = a[HW4], a2 = a[2 * HW4];
    float4 r0 = r[0], r1 = r[HW4], r2 = r[2 * HW4];
    float4 go, ho;
    go.x = (a0.x + a1.x + a2.x) * (1.0f / 3.0f);
    go.y = (a0.y + a1.y + a2.y) * (1.0f / 3.0f);
    go.z = (a0.z + a1.z + a2.z) * (1.0f / 3.0f);
    go.w = (a0.w + a1.w + a2.w) * (1.0f / 3.0f);
    ho.x = (r0.x + r1.x + r2.x) * (1.0f / 3.0f);
    ho.y = (r0.y + r1.y + r2.y) * (1.0f / 3.0f);
    ho.z = (r0.z + r1.z + r2.z) * (1.0f / 3.0f);
    ho.w = (r0.w + r1.w + r2.w) * (1.0f / 3.0f);
    ((float4*)gx)[idx] = go;
    ((float4*)gy)[idx] = ho;
}

// Fused median3(zero-pad) -> Prewitt(VALID) -> GMS map -> block reduce
// -> one plain store of the block partial (NO atomics).
// Also emits this tile's 8x8 2x2-avg-pooled output for the next scale.
__global__ __launch_bounds__(256) void gms_kernel(const float* __restrict__ gx,
                                                  const float* __restrict__ gy,
                                                  int H, int W,
                                                  double* __restrict__ partial,
                                                  float* __restrict__ dx,
                                                  float* __restrict__ dy) {
    __shared__ float sx[20][20];
    __shared__ float sy[20][20];
    __shared__ float mx[18][18];
    __shared__ float my[18][18];

    const int tx = threadIdx.x, ty = threadIdx.y;
    const int tid = ty * 16 + tx;
    const int OI = blockIdx.y * 16, OJ = blockIdx.x * 16;
    const int b = blockIdx.z;
    const float* X = gx + (size_t)b * H * W;
    const float* Y = gy + (size_t)b * H * W;

    for (int l = tid; l < 400; l += 256) {
        int lr = l / 20, lc = l - lr * 20;
        int gr = OI - 1 + lr, gc = OJ - 1 + lc;
        bool in = (gr >= 0) && (gr < H) && (gc >= 0) && (gc < W);
        size_t o = (size_t)gr * W + gc;
        sx[lr][lc] = in ? X[o] : 0.0f;
        sy[lr][lc] = in ? Y[o] : 0.0f;
    }
    __syncthreads();

    // Fused 2x2 avg-pool output for next scale (tile rows OI..OI+15 are all
    // in-bounds since grid*16 == H exactly at every scale).
    if (dx != nullptr && tid < 64) {
        int r = tid >> 3, c = tid & 7;
        int lr = 1 + 2 * r, lc = 1 + 2 * c;
        float px = (sx[lr][lc] + sx[lr][lc + 1] + sx[lr + 1][lc] + sx[lr + 1][lc + 1]) * 0.25f;
        float py = (sy[lr][lc] + sy[lr][lc + 1] + sy[lr + 1][lc] + sy[lr + 1][lc + 1]) * 0.25f;
        int Hd = H >> 1, Wd = W >> 1;
        size_t o = ((size_t)b * Hd + (OI >> 1) + r) * Wd + (OJ >> 1) + c;
        dx[o] = px;
        dy[o] = py;
    }

    for (int l = tid; l < 324; l += 256) {
        int mr = l / 18, mc = l - mr * 18;
        mx[mr][mc] = median9(sx[mr][mc],     sx[mr][mc + 1],     sx[mr][mc + 2],
                             sx[mr + 1][mc], sx[mr + 1][mc + 1], sx[mr + 1][mc + 2],
                             sx[mr + 2][mc], sx[mr + 2][mc + 1], sx[mr + 2][mc + 2]);
        my[mr][mc] = median9(sy[mr][mc],     sy[mr][mc + 1],     sy[mr][mc + 2],
                             sy[mr + 1][mc], sy[mr + 1][mc + 1], sy[mr + 1][mc + 2],
                             sy[mr + 2][mc], sy[mr + 2][mc + 1], sy[mr + 2][mc + 2]);
    }
    __syncthreads();

    float val = 0.0f;
    int i = OI + ty, j = OJ + tx;
    if (i < H - 2 && j < W - 2) {
        float a00 = mx[ty][tx],     a01 = mx[ty][tx + 1],     a02 = mx[ty][tx + 2];
        float a10 = mx[ty + 1][tx],                           a12 = mx[ty + 1][tx + 2];
        float a20 = mx[ty + 2][tx], a21 = mx[ty + 2][tx + 1], a22 = mx[ty + 2][tx + 2];
        float GxI = ((a02 + a12 + a22) - (a00 + a10 + a20)) * (1.0f / 3.0f);
        float GyI = ((a00 + a01 + a02) - (a20 + a21 + a22)) * (1.0f / 3.0f);
        float gI = sqrtf(GxI * GxI + GyI * GyI);

        float b00 = my[ty][tx],     b01 = my[ty][tx + 1],     b02 = my[ty][tx + 2];
        float b10 = my[ty + 1][tx],                           b12 = my[ty + 1][tx + 2];
        float b20 = my[ty + 2][tx], b21 = my[ty + 2][tx + 1], b22 = my[ty + 2][tx + 2];
        float GxR = ((b02 + b12 + b22) - (b00 + b10 + b20)) * (1.0f / 3.0f);
        float GyR = ((b00 + b01 + b02) - (b20 + b21 + b22)) * (1.0f / 3.0f);
        float gR = sqrtf(GxR * GxR + GyR * GyR);

        val = 1.0f - (2.0f * gI * gR + C_GMS) / (gI * gI + gR * gR + C_GMS);
    }

    // wave64 shuffle reduce -> cross-wave LDS -> one plain store per block
    for (int off = 32; off > 0; off >>= 1) val += __shfl_down(val, off);
    __shared__ float wsum[4];
    int lane = tid & 63, wid = tid >> 6;
    if (lane == 0) wsum[wid] = val;
    __syncthreads();
    if (tid == 0) {
        float s = wsum[0] + wsum[1] + wsum[2] + wsum[3];
        int blkId = (blockIdx.z * gridDim.y + blockIdx.y) * gridDim.x + blockIdx.x;
        partial[blkId] = (double)s;
    }
}

// Single block: weighted sum of all per-block partials.
__global__ __launch_bounds__(256) void finalize_kernel(const double* __restrict__ P0, int n0,
                                                       const double* __restrict__ P1, int n1,
                                                       const double* __restrict__ P2, int n2,
                                                       const double* __restrict__ P3, int n3,
                                                       float* __restrict__ out) {
    const int tid = threadIdx.x;
    const double w0 = 1.0 / (16.0 * 510.0 * 510.0 * 4.0);
    const double w1 = 1.0 / (16.0 * 254.0 * 254.0 * 4.0);
    const double w2 = 1.0 / (16.0 * 126.0 * 126.0 * 4.0);
    const double w3 = 1.0 / (16.0 * 62.0 * 62.0 * 4.0);
    double v = 0.0;
    for (int i = tid; i < n0; i += 256) v += P0[i] * w0;
    for (int i = tid; i < n1; i += 256) v += P1[i] * w1;
    for (int i = tid; i < n2; i += 256) v += P2[i] * w2;
    for (int i = tid; i < n3; i += 256) v += P3[i] * w3;
    for (int off = 32; off > 0; off >>= 1) v += __shfl_down(v, off);
    __shared__ double wsum[4];
    int lane = tid & 63, wid = tid >> 6;
    if (lane == 0) wsum[wid] = v;
    __syncthreads();
    if (tid == 0) out[0] = (float)(wsum[0] + wsum[1] + wsum[2] + wsum[3]);
}

extern "C" void kernel_launch(void* const* d_in, const int* in_sizes, int n_in,
                              void* d_out, int out_size, void* d_ws, size_t ws_size,
                              hipStream_t stream) {
    const float* Ii = (const float*)d_in[0];
    const float* Ir = (const float*)d_in[1];
    float* out = (float*)d_out;

    const int B = 16;
    const size_t N0 = (size_t)B * 512 * 512;
    const size_t N1 = (size_t)B * 256 * 256;
    const size_t N2 = (size_t)B * 128 * 128;
    const size_t N3 = (size_t)B * 64 * 64;

    // Per-block partial counts per scale (grid = ceil((H-2)/16)^2 * B)
    const int n0 = 32 * 32 * B;   // 16384
    const int n1 = 16 * 16 * B;   // 4096
    const int n2 = 8 * 8 * B;     // 1024
    const int n3 = 4 * 4 * B;     // 256

    char* ws = (char*)d_ws;
    double* P0 = (double*)ws;
    double* P1 = P0 + n0;
    double* P2 = P1 + n1;
    double* P3 = P2 + n2;
    float* buf = (float*)(ws + (size_t)(n0 + n1 + n2 + n3) * sizeof(double));
    float* X0 = buf;            float* Y0 = X0 + N0;
    float* X1 = Y0 + N0;        float* Y1 = X1 + N1;
    float* X2 = Y1 + N1;        float* Y2 = X2 + N2;
    float* X3 = Y2 + N2;        float* Y3 = X3 + N3;

    const int HW4 = 512 * 512 / 4;
    const int total4 = (int)(N0 / 4);
    gray_kernel<<<(total4 + 255) / 256, 256, 0, stream>>>(Ii, Ir, X0, Y0, HW4, total4);

    gms_kernel<<<dim3(32, 32, B), dim3(16, 16), 0, stream>>>(X0, Y0, 512, 512, P0, X1, Y1);
    gms_kernel<<<dim3(16, 16, B), dim3(16, 16), 0, stream>>>(X1, Y1, 256, 256, P1, X2, Y2);
    gms_kernel<<<dim3(8, 8, B),   dim3(16, 16), 0, stream>>>(X2, Y2, 128, 128, P2, X3, Y3);
    gms_kernel<<<dim3(4, 4, B),   dim3(16, 16), 0, stream>>>(X3, Y3, 64, 64, P3, nullptr, nullptr);

    finalize_kernel<<<1, 256, 0, stream>>>(P0, n0, P1, n1, P2, n2, P3, n3, out);
}

// Round 3
// 194.907 us; speedup vs baseline: 2.1412x; 1.0856x over previous
//
#include <hip/hip_runtime.h>

#define C_GMS 0.0026f

__device__ __forceinline__ float med3f(float a, float b, float c) {
    // exact median-of-3 (selection network); compiler folds to v_med3_f32
    return fmaxf(fminf(a, b), fminf(fmaxf(a, b), c));
}
__device__ __forceinline__ float min3f(float a, float b, float c) {
    return fminf(fminf(a, b), c);
}
__device__ __forceinline__ float max3f(float a, float b, float c) {
    return fmaxf(fmaxf(a, b), c);
}

// One wave owns a 64-column strip (60 output cols), rolls down RC output rows.
// All median/Prewitt state in registers; cross-column via __shfl. No LDS.
// Median9 = med3(max3(col lows), med3(col meds), min3(col highs)) -- exact.
template<bool RGB, bool POOL, int RC>
__global__ __launch_bounds__(256) void gms_scale_kernel(
    const float* __restrict__ srcX, const float* __restrict__ srcY,
    int H, int W, int nstrips, int nchunks, int nunits,
    float* __restrict__ partial,
    float* __restrict__ dX, float* __restrict__ dY)
{
    const int tid  = threadIdx.x;
    const int lane = tid & 63;
    const int u = blockIdx.x * 4 + (tid >> 6);
    if (u >= nunits) return;

    // strip index fastest so the 4 waves of a block are adjacent strips
    // (halo lines shared in L1/L2 of the same CU)
    const int s  = u % nstrips;
    const int t1 = u / nstrips;
    const int k  = t1 % nchunks;
    const int b  = t1 / nchunks;

    const int c0 = 60 * s - 1;          // leftmost gray col held by lane 0
    const int c  = c0 + lane;           // my gray column
    const int R0 = k * RC;              // first output row of this chunk
    const int iend = min(R0 + RC, H - 2);

    const size_t HW = (size_t)H * W;
    const float* PX = srcX + (size_t)b * (RGB ? 3 * HW : HW);
    const float* PY = srcY + (size_t)b * (RGB ? 3 * HW : HW);

    const bool cok = (c >= 0) && (c < W);

    auto loadrow = [&](const float* __restrict__ P, int r) -> float {
        float v = 0.0f;
        if (r >= 0 && r < H) {          // wave-uniform branch
            if (cok) {                   // per-lane (zero-pad cols)
                size_t o = (size_t)r * W + c;
                if (RGB) v = (P[o] + P[o + HW] + P[o + 2 * HW]) * (1.0f / 3.0f);
                else     v = P[o];
            }
        }
        return v;
    };

    // column triple sort + cross-column combine + rowsum (for Prewitt Gy)
    auto medrow = [&](float ga, float gb, float gc, float& m, float& rs) {
        float lo = min3f(ga, gb, gc);
        float me = med3f(ga, gb, gc);
        float hi = max3f(ga, gb, gc);
        float lol = __shfl(lo, lane - 1, 64), lor = __shfl(lo, lane + 1, 64);
        float mel = __shfl(me, lane - 1, 64), mer = __shfl(me, lane + 1, 64);
        float hil = __shfl(hi, lane - 1, 64), hir = __shfl(hi, lane + 1, 64);
        m  = med3f(max3f(lol, lo, lor), med3f(mel, me, mer), min3f(hil, hi, hir));
        rs = m + __shfl(m, lane - 1, 64) + __shfl(m, lane + 1, 64);
    };

    const int Hd = H >> 1, Wd = W >> 1;
    const int phalf = R0 >> 1;
    const int pend  = min(phalf + (RC >> 1), Hd);
    const bool poolLane = ((lane & 1) == 1) && (lane <= 59) && (c + 1 < W);

    // 2x2 avg-pool of gray rows (rb, rc) -> pooled row p (fused downsample)
    auto dopool = [&](float bx, float cx, float by, float cy, int p) {
        if (!POOL) return;
        if (p < phalf || p >= pend) return;   // uniform
        float ux = bx + cx, uy = by + cy;
        float hx = ux + __shfl(ux, lane + 1, 64);
        float hy = uy + __shfl(uy, lane + 1, 64);
        if (poolLane) {
            size_t o = ((size_t)b * Hd + p) * Wd + (c >> 1);
            dX[o] = hx * 0.25f;
            dY[o] = hy * 0.25f;
        }
    };

    // warmup: gray rows R0-1 .. R0+3 -> median rows R0..R0+2
    float xa = loadrow(PX, R0 - 1), ya = loadrow(PY, R0 - 1);
    float xb = loadrow(PX, R0),     yb = loadrow(PY, R0);
    float xc = loadrow(PX, R0 + 1), yc = loadrow(PY, R0 + 1);
    float xd = loadrow(PX, R0 + 2), yd = loadrow(PY, R0 + 2);
    float xe = loadrow(PX, R0 + 3), ye = loadrow(PY, R0 + 3);

    float mx0, mx1, mx2, rx0, rx1, rx2;
    float my0, my1, my2, ry0, ry1, ry2;
    medrow(xa, xb, xc, mx0, rx0); medrow(ya, yb, yc, my0, ry0);
    dopool(xb, xc, yb, yc, phalf);                 // pool rows (R0, R0+1)
    medrow(xb, xc, xd, mx1, rx1); medrow(yb, yc, yd, my1, ry1);
    medrow(xc, xd, xe, mx2, rx2); medrow(yc, yd, ye, my2, ry2);

    float gx2 = xd, gx3 = xe, gy2 = yd, gy3 = ye;  // gray rows i+2, i+3

    // output col j = c-1, valid lanes 2..61 and j <= W-3
    const bool outLane = (lane >= 2) && (lane <= 61) && (c <= W - 2);
    float acc = 0.0f;

    for (int i = R0; i < iend; ++i) {
        float nx = loadrow(PX, i + 4);             // prefetch next gray row
        float ny = loadrow(PY, i + 4);

        // Prewitt + GMS for output row i (uses median rows i..i+2)
        float csx = mx0 + mx1 + mx2;
        float csy = my0 + my1 + my2;
        float Gxx = __shfl(csx, lane + 1, 64) - __shfl(csx, lane - 1, 64);
        float Gxy = __shfl(csy, lane + 1, 64) - __shfl(csy, lane - 1, 64);
        float Gyx = rx0 - rx2;
        float Gyy = ry0 - ry2;
        float gI = sqrtf(Gxx * Gxx + Gyx * Gyx) * (1.0f / 3.0f);
        float gR = sqrtf(Gxy * Gxy + Gyy * Gyy) * (1.0f / 3.0f);
        float gmap = (2.0f * gI * gR + C_GMS) / (gI * gI + gR * gR + C_GMS);
        if (outLane) acc += 1.0f - gmap;

        if (((i + 3) & 1) == 1) dopool(gx2, gx3, gy2, gy3, (i + 2) >> 1);

        // median row i+3 from gray rows i+2..i+4
        float mxn, rxn, myn, ryn;
        medrow(gx2, gx3, nx, mxn, rxn);
        medrow(gy2, gy3, ny, myn, ryn);
        mx0 = mx1; mx1 = mx2; mx2 = mxn; rx0 = rx1; rx1 = rx2; rx2 = rxn;
        my0 = my1; my1 = my2; my2 = myn; ry0 = ry1; ry1 = ry2; ry2 = ryn;
        gx2 = gx3; gx3 = nx; gy2 = gy3; gy3 = ny;
    }

    for (int off = 32; off; off >>= 1) acc += __shfl_down(acc, off, 64);
    if (lane == 0) partial[u] = acc;               // plain store, no atomics
}

__global__ __launch_bounds__(256) void finalize_kernel(
    const float* __restrict__ P, int n0, int n1, int n2, int n3,
    double w0, double w1, double w2, double w3, float* __restrict__ out)
{
    const int tid = threadIdx.x;
    const int e0 = n0, e1 = n0 + n1, e2 = e1 + n2, e3 = e2 + n3;
    double v = 0.0;
    for (int i = tid; i < e3; i += 256) {
        double w = (i < e0) ? w0 : (i < e1) ? w1 : (i < e2) ? w2 : w3;
        v += (double)P[i] * w;
    }
    for (int off = 32; off; off >>= 1) v += __shfl_down(v, off, 64);
    __shared__ double wsum[4];
    int lane = tid & 63, wid = tid >> 6;
    if (lane == 0) wsum[wid] = v;
    __syncthreads();
    if (tid == 0) out[0] = (float)(wsum[0] + wsum[1] + wsum[2] + wsum[3]);
}

extern "C" void kernel_launch(void* const* d_in, const int* in_sizes, int n_in,
                              void* d_out, int out_size, void* d_ws, size_t ws_size,
                              hipStream_t stream) {
    const float* Ii = (const float*)d_in[0];
    const float* Ir = (const float*)d_in[1];
    float* out = (float*)d_out;
    const int B = 16;

    // units = B * nstrips * nchunks; nstrips = ceil((W-2)/60), nchunks = ceil((H-2)/RC)
    const int n0 = B * 9 * 16;   // 512: RC=32 -> 2304
    const int n1 = B * 5 * 32;   // 256: RC=8  -> 2560
    const int n2 = B * 3 * 16;   // 128: RC=8  -> 768
    const int n3 = B * 2 * 8;    //  64: RC=8  -> 256

    char* ws = (char*)d_ws;
    float* P  = (float*)ws;                 // 5888 partials (one per wave)
    float* X1 = P + 8192;
    float* Y1 = X1 + B * 256 * 256;
    float* X2 = Y1 + B * 256 * 256;
    float* Y2 = X2 + B * 128 * 128;
    float* X3 = Y2 + B * 128 * 128;
    float* Y3 = X3 + B * 64 * 64;

    gms_scale_kernel<true,  true,  32><<<n0 / 4, 256, 0, stream>>>(Ii, Ir, 512, 512, 9, 16, n0, P, X1, Y1);
    gms_scale_kernel<false, true,  8><<<n1 / 4, 256, 0, stream>>>(X1, Y1, 256, 256, 5, 32, n1, P + n0, X2, Y2);
    gms_scale_kernel<false, true,  8><<<n2 / 4, 256, 0, stream>>>(X2, Y2, 128, 128, 3, 16, n2, P + n0 + n1, X3, Y3);
    gms_scale_kernel<false, false, 8><<<n3 / 4, 256, 0, stream>>>(X3, Y3, 64, 64, 2, 8, n3, P + n0 + n1 + n2, nullptr, nullptr);

    const double w0 = 1.0 / (16.0 * 510.0 * 510.0 * 4.0);
    const double w1 = 1.0 / (16.0 * 254.0 * 254.0 * 4.0);
    const double w2 = 1.0 / (16.0 * 126.0 * 126.0 * 4.0);
    const double w3 = 1.0 / (16.0 * 62.0 * 62.0 * 4.0);
    finalize_kernel<<<1, 256, 0, stream>>>(P, n0, n1, n2, n3, w0, w1, w2, w3, out);
}